// Round 19
// baseline (3722.436 us; speedup 1.0000x reference)
//
#include <hip/hip_runtime.h>
#include <math.h>

#define NA 16384
#define NB 64
#define NE 262144
#define NT 1048576
#define NR 128
#define DA 128
#define DEM 256
#define DTR 32
#define DC 16
#define DBIL 64
#define DNKR 128
#define DDP 8
#define NK 32
#define APM 256
#define PI_F 3.14159265358979323846f

typedef unsigned short u16;
typedef unsigned int u32;
typedef __attribute__((ext_vector_type(8))) short bf16x8;
typedef __attribute__((ext_vector_type(4))) float f32x4;

__device__ __forceinline__ float silu_f(float x){ return x / (1.0f + __expf(-x)); }
__device__ __forceinline__ float us2f(u32 u){ return __uint_as_float(u<<16); }
__device__ __forceinline__ u16 f2us(float f){
  u32 x = __float_as_uint(f);
  u32 r = x + 0x7fffu + ((x>>16)&1u);
  return (u16)(r>>16);
}
__device__ __forceinline__ void unp8(uint4 v, float* o){
  o[0]=us2f(v.x&0xffffu); o[1]=us2f(v.x>>16);
  o[2]=us2f(v.y&0xffffu); o[3]=us2f(v.y>>16);
  o[4]=us2f(v.z&0xffffu); o[5]=us2f(v.z>>16);
  o[6]=us2f(v.w&0xffffu); o[7]=us2f(v.w>>16);
}
__device__ __forceinline__ uint4 pack8(const float* v){
  uint4 r;
  r.x = (u32)f2us(v[0]) | ((u32)f2us(v[1])<<16);
  r.y = (u32)f2us(v[2]) | ((u32)f2us(v[3])<<16);
  r.z = (u32)f2us(v[4]) | ((u32)f2us(v[5])<<16);
  r.w = (u32)f2us(v[6]) | ((u32)f2us(v[7])<<16);
  return r;
}
__device__ __forceinline__ float rbf_val(float d, int r){
  float ds = d*(1.0f/6.0f);
  float env = 0.0f;
  if (ds < 1.0f){
    float p2 = ds*ds, p5 = p2*p2*ds;
    env = 1.0f - 21.0f*p5 + 35.0f*p5*ds - 15.0f*p5*p2;
  }
  return env * 0.5773502691896258f * __sinf((float)(r+1)*PI_F*ds) / d;
}

// ---- swizzled bf16 LDS tile helpers (16B slot index ^= row&7) ----
__device__ __forceinline__ bf16x8 ldsA(const u16* sA, int row, int KLD, int slot){
  int s = slot ^ (row&7);
  return *(const bf16x8*)(sA + row*KLD + s*8);
}
__device__ __forceinline__ void stSlot(u16* sA, int row, int KLD, int slot, uint4 v){
  int s = slot ^ (row&7);
  *(uint4*)(sA + row*KLD + s*8) = v;
}
__device__ __forceinline__ void stW(u16* sA, int row, int KLD, int col, u16 v){
  int s = (col>>3) ^ (row&7);
  sA[row*KLD + s*8 + (col&7)] = v;
}
__device__ __forceinline__ bf16x8 ldB(const u16* Wt, int col, int K, int koff){
  return *(const bf16x8*)(Wt + (size_t)col*K + koff);
}

// ---------------- utility ----------------
__global__ void k_zero(int* __restrict__ p, int n){
  int i = blockIdx.x*256+threadIdx.x; if (i<n) p[i]=0;
}

// ---------------- merged weight prep: fp32 [K][N] -> bf16 [N][Kpad] ----------------
struct WprepDesc { const float* src; u16* dst; int K; int N; int Kpad; int elems; };
struct WprepTable { WprepDesc d[15]; int n; };
__global__ void k_wprep_all(WprepTable t){
  long long i = (long long)blockIdx.x*256 + threadIdx.x;
  for (int q=0;q<15;q++){
    if (q >= t.n) return;
    int e = t.d[q].elems;
    if (i < e){
      int Kpad = t.d[q].Kpad;
      int n = (int)(i / Kpad), k = (int)(i - (long long)n*Kpad);
      t.d[q].dst[(size_t)n*Kpad + k] =
        (k < t.d[q].K)? f2us(t.d[q].src[(size_t)k*t.d[q].N + n]) : (u16)0;
      return;
    }
    i -= e;
  }
}
__global__ void k_wprep_cbf(const float* __restrict__ src, u16* __restrict__ dst){
  int i = blockIdx.x*256+threadIdx.x;
  if (i >= 112*128) return;
  int n = i>>7, k = i&127;
  int s = n>>4, c = n&15;
  dst[i] = f2us(src[s*2048 + k*16 + c]);
}

// ---------------- permutation helpers ----------------
__global__ void k_iperm(const int* __restrict__ list, int n, int* __restrict__ iperm){
  int i = blockIdx.x*256+threadIdx.x;
  if (i<n) iperm[list[i]] = i;
}
__global__ void k_permute2(const int* __restrict__ list, const int* __restrict__ a,
                           const int* __restrict__ b, int n,
                           int* __restrict__ ap, int* __restrict__ bp){
  int i = blockIdx.x*256+threadIdx.x;
  if (i<n){ int e = list[i]; ap[i]=a[e]; bp[i]=b[e]; }
}
__global__ void k_count_map(const int* __restrict__ ids, const int* __restrict__ map,
                            int num, int* __restrict__ cnt){
  int i = blockIdx.x*256+threadIdx.x;
  if (i<num) atomicAdd(&cnt[map[ids[i]]],1);
}
// fill + per-triplet Legendre precompute: P[p] = {x, P2..P6, 0, 0} bf16
__global__ void k_fill_valmap_P(const int* __restrict__ ids, const int* __restrict__ vals,
                                const int* __restrict__ map, const float4* __restrict__ vecd,
                                int num, int* __restrict__ cur, int* __restrict__ list,
                                u16* __restrict__ Ppre){
  int i = blockIdx.x*256+threadIdx.x;
  if (i>=num) return;
  int eca = map[ids[i]];
  int eba = map[vals[i]];
  int p = atomicAdd(&cur[eca],1);
  list[p] = eba;
  float4 va = vecd[eca], vb = vecd[eba];
  float x = (va.x*vb.x + va.y*vb.y + va.z*vb.z)*va.w*vb.w;   // both .w = 1/d
  x = fminf(1.0f, fmaxf(-1.0f, x));
  float p2 = (3.f*x*x - 1.f)*0.5f;
  float p3 = (5.f*x*p2 - 2.f*x)*(1.0f/3.0f);
  float p4 = (7.f*x*p3 - 3.f*p2)*0.25f;
  float p5 = (9.f*x*p4 - 4.f*p3)*0.2f;
  float p6 = (11.f*x*p5 - 5.f*p4)*(1.0f/6.0f);
  uint4 pk;
  pk.x = (u32)f2us(x)  | ((u32)f2us(p2)<<16);
  pk.y = (u32)f2us(p3) | ((u32)f2us(p4)<<16);
  pk.z = (u32)f2us(p5) | ((u32)f2us(p6)<<16);
  pk.w = 0u;
  *(uint4*)(Ppre + (size_t)p*8) = pk;
}

// ---------------- geometry (permuted edge order): vec + 1/d ----------------
__global__ void k_geom(const float* __restrict__ pos, const int* __restrict__ src,
                       const int* __restrict__ tgt, float4* __restrict__ vecd,
                       float* __restrict__ dlen){
  int e = blockIdx.x*256+threadIdx.x;
  if (e >= NE) return;
  int s = src[e], t = tgt[e];
  float vx = pos[s*3+0]-pos[t*3+0];
  float vy = pos[s*3+1]-pos[t*3+1];
  float vz = pos[s*3+2]-pos[t*3+2];
  float d = sqrtf(vx*vx+vy*vy+vz*vz + 1e-12f);
  vecd[e] = make_float4(vx,vy,vz,1.0f/d);
  dlen[e] = d;
}

// ---------------- r16a/h/o (bf16 out) ----------------
__global__ void __launch_bounds__(256)
k_rbf16(const float* __restrict__ dlen, const float* __restrict__ W1,
        const float* __restrict__ W2, const float* __restrict__ W3,
        u16* __restrict__ r16a, u16* __restrict__ r16h, u16* __restrict__ r16o){
  __shared__ float rb[4*128];
  int e0 = blockIdx.x*4;
  int tid = threadIdx.x, eg = tid>>6, lt = tid&63;
  int e = e0+eg;
  float d = dlen[e];
  rb[eg*128+lt]    = rbf_val(d, lt);
  rb[eg*128+lt+64] = rbf_val(d, lt+64);
  __syncthreads();
  if (lt < 48){
    int which = lt>>4, jj = lt&15;
    const float* W = (which==0)? W1 : (which==1)? W2 : W3;
    float acc=0.f;
    for (int r=0;r<NR;r++) acc += rb[eg*128+r]*W[r*16+jj];
    u16* o = (which==0)? r16a : (which==1)? r16h : r16o;
    o[(size_t)e*16+jj] = f2us(acc);
  }
}

// ---------------- h = atom_table[z] ----------------
__global__ void k_gather_h(const float* __restrict__ table, const int* __restrict__ z,
                           float* __restrict__ h){
  int idx = blockIdx.x*256 + threadIdx.x;
  int n = idx >> 7, a = idx & 127;
  h[idx] = table[z[n]*DA + a];
}

// ---------------- kdot cos/sin ----------------
__global__ void k_kdot(const float* __restrict__ pos, const float* __restrict__ kg,
                       float* __restrict__ cosk, float* __restrict__ sink_){
  int idx = blockIdx.x*256+threadIdx.x;
  int n = idx>>5, k = idx&31;
  float dotv = pos[n*3]*kg[k*3]+pos[n*3+1]*kg[k*3+1]+pos[n*3+2]*kg[k*3+2];
  float s, c;
  sincosf(dotv, &s, &c);
  cosk[idx] = c; sink_[idx] = s;
}

// ---------------- kf ----------------
__global__ void k_kf(const float* __restrict__ krbf, const float* __restrict__ Wd,
                     const float* __restrict__ Wf, float* __restrict__ kf){
  __shared__ float t[NK*DDP];
  int tid = threadIdx.x;
  { int k = tid>>3, d = tid&7;
    float s=0.f;
    for (int r=0;r<DNKR;r++) s += krbf[k*DNKR+r]*Wd[r*DDP+d];
    t[tid] = silu_f(s); }
  __syncthreads();
  for (int idx=tid; idx<NK*DA; idx+=256){
    int k = idx>>7, a = idx&127;
    float s=0.f;
    #pragma unroll
    for (int d=0; d<DDP; d++) s += t[k*DDP+d]*Wf[d*DA+a];
    kf[idx]=s;
  }
}

// ---------------- CSR build ----------------
__global__ void k_count(const int* __restrict__ ids, int num, int* __restrict__ cnt){
  int i = blockIdx.x*256+threadIdx.x;
  if (i<num) atomicAdd(&cnt[ids[i]],1);
}
__global__ void k_scan1(const int* __restrict__ cnt, int n, int* __restrict__ loc,
                        int* __restrict__ part){
  __shared__ int lds[256];
  int i = blockIdx.x*256+threadIdx.x;
  int v = (i<n)?cnt[i]:0;
  lds[threadIdx.x]=v; __syncthreads();
  for (int off=1; off<256; off<<=1){
    int tv = (threadIdx.x >= (unsigned)off)? lds[threadIdx.x-off]:0;
    __syncthreads();
    lds[threadIdx.x]+=tv;
    __syncthreads();
  }
  if (i<n) loc[i] = lds[threadIdx.x]-v;
  if (threadIdx.x==255) part[blockIdx.x]=lds[255];
}
__global__ void k_scan2(int* __restrict__ part, int nparts){
  __shared__ int lds[1024];
  int tid=threadIdx.x;
  for (int i=tid;i<1024;i+=256) lds[i] = (i<nparts)? part[i] : 0;
  __syncthreads();
  if (tid==0){
    int run=0;
    for (int i=0;i<nparts;i++){ int v=lds[i]; lds[i]=run; run+=v; }
  }
  __syncthreads();
  for (int i=tid;i<1024;i+=256) if (i<nparts) part[i]=lds[i];
}
__global__ void k_scan3(const int* __restrict__ loc, const int* __restrict__ part,
                        const int* __restrict__ cnt, int n, int* __restrict__ off){
  int i = blockIdx.x*256+threadIdx.x;
  if (i<n){ int o = loc[i]+part[i>>8]; off[i]=o; if (i==n-1) off[n]=o+cnt[i]; }
}
__global__ void k_copy_int(const int* __restrict__ a, int n, int* __restrict__ b){
  int i=blockIdx.x*256+threadIdx.x; if(i<n) b[i]=a[i];
}
__global__ void k_fill(const int* __restrict__ ids, int num, int* __restrict__ cur,
                       int* __restrict__ list){
  int i = blockIdx.x*256+threadIdx.x;
  if (i<num){ int p = atomicAdd(&cur[ids[i]],1); list[p]=i; }
}

// ================= MFMA edge-GEMM family =================

// ---------------- initial edge embedding (K=384, phased 256+128) ----------------
__global__ void __launch_bounds__(256)
k_edgeinit_mx(const float* __restrict__ h, const float* __restrict__ dlen,
              const u16* __restrict__ Wt, const float* __restrict__ bias,
              const int* __restrict__ src, const int* __restrict__ tgt,
              u16* __restrict__ outm){
  __shared__ u16 sA[64*256];   // 32 KB
  int e0 = blockIdx.x*64;
  int j = threadIdx.x, lane = j&63, w = j>>6;
  int rbase = (w&1)*32, cbase = (w>>1)*128;
  int l15 = lane&15, kg = lane>>4;
  f32x4 acc[2][8];
  #pragma unroll
  for (int rt=0;rt<2;rt++)
    #pragma unroll
    for (int i=0;i<8;i++) acc[rt][i] = (f32x4){0.f,0.f,0.f,0.f};
  for (int idx=j; idx<64*32; idx+=256){
    int row = idx>>5, slot = idx&31;
    int e = e0+row;
    const float* srcp = (slot<16)? (h + (size_t)src[e]*DA + slot*8)
                                 : (h + (size_t)tgt[e]*DA + (slot-16)*8);
    float v[8];
    float4 q0 = *(const float4*)srcp, q1 = *(const float4*)(srcp+4);
    v[0]=q0.x; v[1]=q0.y; v[2]=q0.z; v[3]=q0.w;
    v[4]=q1.x; v[5]=q1.y; v[6]=q1.z; v[7]=q1.w;
    stSlot(sA, row, 256, slot, pack8(v));
  }
  __syncthreads();
  #pragma unroll 2
  for (int kc=0; kc<8; kc++){
    bf16x8 a0 = ldsA(sA, rbase+l15,    256, kc*4+kg);
    bf16x8 a1 = ldsA(sA, rbase+16+l15, 256, kc*4+kg);
    #pragma unroll
    for (int ct=0; ct<8; ct++){
      bf16x8 b = ldB(Wt, cbase+ct*16+l15, 384, kc*32+kg*8);
      acc[0][ct] = __builtin_amdgcn_mfma_f32_16x16x32_bf16(a0, b, acc[0][ct], 0,0,0);
      acc[1][ct] = __builtin_amdgcn_mfma_f32_16x16x32_bf16(a1, b, acc[1][ct], 0,0,0);
    }
  }
  __syncthreads();
  for (int idx=j; idx<64*16; idx+=256){
    int row = idx>>4, slot = idx&15;
    float dv = dlen[e0+row];
    float v[8];
    #pragma unroll
    for (int q=0;q<8;q++) v[q] = rbf_val(dv, slot*8+q);
    stSlot(sA, row, 256, slot, pack8(v));
  }
  __syncthreads();
  #pragma unroll 2
  for (int kc=8; kc<12; kc++){
    bf16x8 a0 = ldsA(sA, rbase+l15,    256, (kc-8)*4+kg);
    bf16x8 a1 = ldsA(sA, rbase+16+l15, 256, (kc-8)*4+kg);
    #pragma unroll
    for (int ct=0; ct<8; ct++){
      bf16x8 b = ldB(Wt, cbase+ct*16+l15, 384, kc*32+kg*8);
      acc[0][ct] = __builtin_amdgcn_mfma_f32_16x16x32_bf16(a0, b, acc[0][ct], 0,0,0);
      acc[1][ct] = __builtin_amdgcn_mfma_f32_16x16x32_bf16(a1, b, acc[1][ct], 0,0,0);
    }
  }
  #pragma unroll
  for (int rt=0;rt<2;rt++)
  #pragma unroll
  for (int ct=0; ct<8; ct++){
    int col = cbase + ct*16 + l15;
    float bv = bias[col];
    #pragma unroll
    for (int r=0;r<4;r++){
      int row = rbase + rt*16 + kg*4 + r;
      outm[(size_t)(e0+row)*DEM + col] = f2us(silu_f(acc[rt][ct][r] + bv));
    }
  }
}

// ---- fused: T1=silu(m@W_ba)*(r16@W_r3e); xtrip=silu(T1@W_dt)  (32 rows) ----
__global__ void __launch_bounds__(256)
k_ba_dt_mx(const u16* __restrict__ m, const u16* __restrict__ WtBA,
           const u16* __restrict__ r16, const u16* __restrict__ WtR3E,
           const u16* __restrict__ WtDT, u16* __restrict__ xtrip){
  __shared__ u16 sM[32*256];
  __shared__ u16 sR[32*64];
  int e0 = blockIdx.x*32;
  int j = threadIdx.x, lane = j&63, w = j>>6;
  for (int p=j; p<32*32; p+=256){
    int row = p>>5, slot = p&31;
    uint4 v = *(const uint4*)(m + (size_t)(e0+row)*DEM + slot*8);
    stSlot(sM, row, 256, slot, v);
  }
  for (int p=j; p<32*8; p+=256){
    int row = p>>3, slot = p&7;
    uint4 v = {0u,0u,0u,0u};
    if (slot<2) v = *(const uint4*)(r16 + (size_t)(e0+row)*16 + slot*8);
    stSlot(sR, row, 64, slot, v);
  }
  __syncthreads();
  int rbase = (w&1)*16, cbase = (w>>1)*128;
  int l15 = lane&15, kg = lane>>4;
  int arow = rbase + l15;
  f32x4 accA[8], accG[8];
  #pragma unroll
  for (int i=0;i<8;i++){ accA[i]=(f32x4){0.f,0.f,0.f,0.f}; accG[i]=(f32x4){0.f,0.f,0.f,0.f}; }
  #pragma unroll 2
  for (int kc=0; kc<8; kc++){
    bf16x8 a = ldsA(sM, arow, 256, kc*4+kg);
    #pragma unroll
    for (int ct=0; ct<8; ct++){
      bf16x8 b = ldB(WtBA, cbase+ct*16+l15, 256, kc*32+kg*8);
      accA[ct] = __builtin_amdgcn_mfma_f32_16x16x32_bf16(a, b, accA[ct], 0,0,0);
    }
  }
  { bf16x8 a = ldsA(sR, arow, 64, kg);
    #pragma unroll
    for (int ct=0; ct<8; ct++){
      bf16x8 b = ldB(WtR3E, cbase+ct*16+l15, 32, kg*8);
      accG[ct] = __builtin_amdgcn_mfma_f32_16x16x32_bf16(a, b, accG[ct], 0,0,0);
    } }
  __syncthreads();
  #pragma unroll
  for (int ct=0; ct<8; ct++){
    int col = cbase + ct*16 + l15;
    #pragma unroll
    for (int r=0;r<4;r++){
      int row = rbase + kg*4 + r;
      stW(sM, row, 256, col, f2us(silu_f(accA[ct][r])*accG[ct][r]));
    }
  }
  __syncthreads();
  int rb2 = (w&1)*16, ct2 = (w>>1);
  int arow2 = rb2 + l15;
  f32x4 acc2 = (f32x4){0.f,0.f,0.f,0.f};
  #pragma unroll 2
  for (int kc=0; kc<8; kc++){
    bf16x8 a = ldsA(sM, arow2, 256, kc*4+kg);
    bf16x8 b = ldB(WtDT, ct2*16+l15, 256, kc*32+kg*8);
    acc2 = __builtin_amdgcn_mfma_f32_16x16x32_bf16(a, b, acc2, 0,0,0);
  }
  #pragma unroll
  for (int r=0;r<4;r++){
    int row = rb2 + kg*4 + r;
    int col = ct2*16 + l15;
    xtrip[(size_t)(e0+row)*DTR + col] = f2us(silu_f(acc2[r]));
  }
}

// ---------------- triplet bilinear + fused W_up m-update (precomputed P) ----------------
__global__ void __launch_bounds__(256)
k_trip(const int* __restrict__ ca_off, const int* __restrict__ ba_list,
       const u16* __restrict__ Ppre, const float* __restrict__ dlen,
       const u16* __restrict__ WtCBF, const u16* __restrict__ xtrip,
       const u16* __restrict__ WtBIL, const u16* __restrict__ WtUP,
       u16* __restrict__ m){
  __shared__ u16 sS3[16*512];    // 16 KB
  __shared__ u16 sRB[16*128];    // 4 KB
  __shared__ u16 rWl[16*112];    // 3.5 KB (bf16)
  __shared__ u16 sX3[16*64];     // 2 KB
  int e0 = blockIdx.x*16;
  int tid = threadIdx.x, lane = tid&63, w = tid>>6;
  int l15 = lane&15, kg = lane>>4;
  for (int idx=tid; idx<2048; idx+=256){
    int e = idx>>7, r = idx&127;
    stW(sRB, e, 128, r, f2us(rbf_val(dlen[e0+e], r)));
  }
  __syncthreads();
  for (int ct=w; ct<7; ct+=4){
    f32x4 acc = (f32x4){0.f,0.f,0.f,0.f};
    for (int kc=0; kc<4; kc++){
      bf16x8 a = ldsA(sRB, l15, 128, kc*4+kg);
      bf16x8 b = ldB(WtCBF, ct*16+l15, 128, kc*32+kg*8);
      acc = __builtin_amdgcn_mfma_f32_16x16x32_bf16(a, b, acc, 0,0,0);
    }
    #pragma unroll
    for (int r=0;r<4;r++)
      rWl[(kg*4+r)*112 + ct*16 + l15] = f2us(acc[r]);
  }
  __syncthreads();
  int half = lane>>5, tr = lane&31;
  for (int sub=0; sub<4; sub++){
    int el = w*4+sub, e = e0+el;
    float a0=0.f,a1=0.f,a2=0.f,a3=0.f,a4=0.f,a5=0.f,a6=0.f;
    int beg = ca_off[e], end = ca_off[e+1];
    int cnt = end - beg;
    int c0 = (cnt+1)>>1;
    int mybeg = beg + half*c0;
    int myend = half ? end : beg+c0;
    float xk = 0.f;
    if (mybeg<myend){
      int b0 = ba_list[mybeg];
      xk = us2f(xtrip[(size_t)b0*DTR + tr]);
    }
    for (int ti=mybeg; ti<myend; ti++){
      int bn = (ti+1<myend)? ba_list[ti+1] : 0;
      float xk_n = us2f(xtrip[(size_t)bn*DTR + tr]);
      uint4 pk = *(const uint4*)(Ppre + (size_t)ti*8);
      a0 += xk;
      a1 += us2f(pk.x&0xffffu)*xk;
      a2 += us2f(pk.x>>16)*xk;
      a3 += us2f(pk.y&0xffffu)*xk;
      a4 += us2f(pk.y>>16)*xk;
      a5 += us2f(pk.z&0xffffu)*xk;
      a6 += us2f(pk.z>>16)*xk;
      xk = xk_n;
    }
    a0 += __shfl_xor(a0, 32); a1 += __shfl_xor(a1, 32);
    a2 += __shfl_xor(a2, 32); a3 += __shfl_xor(a3, 32);
    a4 += __shfl_xor(a4, 32); a5 += __shfl_xor(a5, 32);
    a6 += __shfl_xor(a6, 32);
    const u16* rwe = rWl + el*112;
    #pragma unroll
    for (int q=0;q<8;q++){
      int c = half*8+q;
      float s3 = us2f(rwe[c])*a0 + us2f(rwe[16+c])*a1 + us2f(rwe[32+c])*a2
               + us2f(rwe[48+c])*a3 + us2f(rwe[64+c])*a4 + us2f(rwe[80+c])*a5
               + us2f(rwe[96+c])*a6;
      stW(sS3, el, 512, c*32+tr, f2us(s3));
    }
  }
  __syncthreads();
  { f32x4 acc = (f32x4){0.f,0.f,0.f,0.f};
    #pragma unroll 2
    for (int kc=0; kc<16; kc++){
      bf16x8 a = ldsA(sS3, l15, 512, kc*4+kg);
      bf16x8 b = ldB(WtBIL, w*16+l15, 512, kc*32+kg*8);
      acc = __builtin_amdgcn_mfma_f32_16x16x32_bf16(a, b, acc, 0,0,0);
    }
    #pragma unroll
    for (int r=0;r<4;r++)
      stW(sX3, kg*4+r, 64, w*16+l15, f2us(acc[r]));
  }
  __syncthreads();
  f32x4 acc2[4];
  #pragma unroll
  for (int i=0;i<4;i++) acc2[i] = (f32x4){0.f,0.f,0.f,0.f};
  for (int kc=0; kc<2; kc++){
    bf16x8 a = ldsA(sX3, l15, 64, kc*4+kg);
    #pragma unroll
    for (int ct=0; ct<4; ct++){
      bf16x8 b = ldB(WtUP, w*64+ct*16+l15, 64, kc*32+kg*8);
      acc2[ct] = __builtin_amdgcn_mfma_f32_16x16x32_bf16(a, b, acc2[ct], 0,0,0);
    }
  }
  #pragma unroll
  for (int ct=0; ct<4; ct++){
    int col = w*64 + ct*16 + l15;
    #pragma unroll
    for (int r=0;r<4;r++){
      int row = kg*4 + r;
      size_t oi = (size_t)(e0+row)*DEM + col;
      m[oi] = f2us((us2f(m[oi]) + silu_f(acc2[ct][r]))*0.7071067811865476f);
    }
  }
}

// ---------------- fused residual MLP (64 rows, 32KB shared buffer) ----------------
__global__ void __launch_bounds__(256)
k_res_mx(const u16* __restrict__ WtR1, const u16* __restrict__ WtR2, u16* __restrict__ m){
  __shared__ u16 sM[64*256];   // 32 KB
  int e0 = blockIdx.x*64;
  int j = threadIdx.x, lane = j&63, w = j>>6;
  for (int p=j; p<64*32; p+=256){
    int row = p>>5, slot = p&31;
    uint4 v = *(const uint4*)(m + (size_t)(e0+row)*DEM + slot*8);
    stSlot(sM, row, 256, slot, v);
  }
  __syncthreads();
  int rbase = (w&1)*32, cbase = (w>>1)*128;
  int l15 = lane&15, kg = lane>>4;
  f32x4 acc[2][8];
  #pragma unroll
  for (int rt=0;rt<2;rt++)
    #pragma unroll
    for (int i=0;i<8;i++) acc[rt][i]=(f32x4){0.f,0.f,0.f,0.f};
  #pragma unroll 2
  for (int kc=0; kc<8; kc++){
    bf16x8 a0 = ldsA(sM, rbase+l15,    256, kc*4+kg);
    bf16x8 a1 = ldsA(sM, rbase+16+l15, 256, kc*4+kg);
    #pragma unroll
    for (int ct=0; ct<8; ct++){
      bf16x8 b = ldB(WtR1, cbase+ct*16+l15, 256, kc*32+kg*8);
      acc[0][ct] = __builtin_amdgcn_mfma_f32_16x16x32_bf16(a0, b, acc[0][ct], 0,0,0);
      acc[1][ct] = __builtin_amdgcn_mfma_f32_16x16x32_bf16(a1, b, acc[1][ct], 0,0,0);
    }
  }
  __syncthreads();
  #pragma unroll
  for (int rt=0;rt<2;rt++)
  #pragma unroll
  for (int ct=0; ct<8; ct++){
    int col = cbase + ct*16 + l15;
    #pragma unroll
    for (int r=0;r<4;r++)
      stW(sM, rbase + rt*16 + kg*4 + r, 256, col, f2us(silu_f(acc[rt][ct][r])));
  }
  __syncthreads();
  #pragma unroll
  for (int rt=0;rt<2;rt++)
    #pragma unroll
    for (int i=0;i<8;i++) acc[rt][i]=(f32x4){0.f,0.f,0.f,0.f};
  #pragma unroll 2
  for (int kc=0; kc<8; kc++){
    bf16x8 a0 = ldsA(sM, rbase+l15,    256, kc*4+kg);
    bf16x8 a1 = ldsA(sM, rbase+16+l15, 256, kc*4+kg);
    #pragma unroll
    for (int ct=0; ct<8; ct++){
      bf16x8 b = ldB(WtR2, cbase+ct*16+l15, 256, kc*32+kg*8);
      acc[0][ct] = __builtin_amdgcn_mfma_f32_16x16x32_bf16(a0, b, acc[0][ct], 0,0,0);
      acc[1][ct] = __builtin_amdgcn_mfma_f32_16x16x32_bf16(a1, b, acc[1][ct], 0,0,0);
    }
  }
  #pragma unroll
  for (int rt=0;rt<2;rt++)
  #pragma unroll
  for (int ct=0; ct<8; ct++){
    int col = cbase + ct*16 + l15;
    #pragma unroll
    for (int r=0;r<4;r++){
      int row = rbase + rt*16 + kg*4 + r;
      size_t oi = (size_t)(e0+row)*DEM + col;
      float orig = us2f(m[oi]);
      m[oi] = f2us((orig + silu_f(acc[rt][ct][r]))*0.7071067811865476f);
    }
  }
}

// ---------------- edge refresh (64 rows, K=512 phased 256+256, 32KB) ----------------
__global__ void __launch_bounds__(256)
k_catref_mx(const float* __restrict__ h, const u16* __restrict__ Wt,
            const int* __restrict__ src, const int* __restrict__ tgt,
            u16* __restrict__ m){
  __shared__ u16 sA[64*256];   // 32 KB
  int e0 = blockIdx.x*64;
  int j = threadIdx.x, lane = j&63, w = j>>6;
  int rbase = (w&1)*32, cbase = (w>>1)*128;
  int l15 = lane&15, kg = lane>>4;
  f32x4 acc[2][8];
  #pragma unroll
  for (int rt=0;rt<2;rt++)
    #pragma unroll
    for (int i=0;i<8;i++) acc[rt][i]=(f32x4){0.f,0.f,0.f,0.f};
  for (int idx=j; idx<64*32; idx+=256){
    int row = idx>>5, slot = idx&31;
    int e = e0+row;
    const float* srcp = (slot<16)? (h + (size_t)src[e]*DA + slot*8)
                                 : (h + (size_t)tgt[e]*DA + (slot-16)*8);
    float v[8];
    float4 q0 = *(const float4*)srcp, q1 = *(const float4*)(srcp+4);
    v[0]=q0.x; v[1]=q0.y; v[2]=q0.z; v[3]=q0.w;
    v[4]=q1.x; v[5]=q1.y; v[6]=q1.z; v[7]=q1.w;
    stSlot(sA, row, 256, slot, pack8(v));
  }
  __syncthreads();
  #pragma unroll 2
  for (int kc=0; kc<8; kc++){
    bf16x8 a0 = ldsA(sA, rbase+l15,    256, kc*4+kg);
    bf16x8 a1 = ldsA(sA, rbase+16+l15, 256, kc*4+kg);
    #pragma unroll
    for (int ct=0; ct<8; ct++){
      bf16x8 b = ldB(Wt, cbase+ct*16+l15, 512, kc*32+kg*8);
      acc[0][ct] = __builtin_amdgcn_mfma_f32_16x16x32_bf16(a0, b, acc[0][ct], 0,0,0);
      acc[1][ct] = __builtin_amdgcn_mfma_f32_16x16x32_bf16(a1, b, acc[1][ct], 0,0,0);
    }
  }
  __syncthreads();
  for (int p=j; p<64*32; p+=256){
    int row = p>>5, slot = p&31;
    uint4 v = *(const uint4*)(m + (size_t)(e0+row)*DEM + slot*8);
    stSlot(sA, row, 256, slot, v);
  }
  __syncthreads();
  #pragma unroll 2
  for (int kc=8; kc<16; kc++){
    bf16x8 a0 = ldsA(sA, rbase+l15,    256, (kc-8)*4+kg);
    bf16x8 a1 = ldsA(sA, rbase+16+l15, 256, (kc-8)*4+kg);
    #pragma unroll
    for (int ct=0; ct<8; ct++){
      bf16x8 b = ldB(Wt, cbase+ct*16+l15, 512, kc*32+kg*8);
      acc[0][ct] = __builtin_amdgcn_mfma_f32_16x16x32_bf16(a0, b, acc[0][ct], 0,0,0);
      acc[1][ct] = __builtin_amdgcn_mfma_f32_16x16x32_bf16(a1, b, acc[1][ct], 0,0,0);
    }
  }
  __syncthreads();
  #pragma unroll
  for (int rt=0;rt<2;rt++)
  #pragma unroll
  for (int ct=0; ct<8; ct++){
    int col = cbase + ct*16 + l15;
    #pragma unroll
    for (int r=0;r<4;r++){
      int row = rbase + rt*16 + kg*4 + r;
      m[(size_t)(e0+row)*DEM + col] = f2us(silu_f(acc[rt][ct][r]));
    }
  }
}

// ---------------- fused gate + segment-sum (SEQUENTIAL: edges tgt-sorted) ----------------
__global__ void __launch_bounds__(256)
k_gseg_seq(const int* __restrict__ off, const u16* __restrict__ m,
           const u16* __restrict__ r16, const float* __restrict__ Wg,
           float* __restrict__ outp){
  __shared__ float sW[16*256];
  int n = blockIdx.x, j = threadIdx.x;
  for (int idx=j; idx<4096; idx+=256) sW[idx] = Wg[idx];
  __syncthreads();
  float s = 0.f;
  int beg = off[n], end = off[n+1];
  for (int e=beg; e<end; e++){
    const uint4* rp = (const uint4*)(r16 + (size_t)e*16);
    float rv[16];
    unp8(rp[0], rv); unp8(rp[1], rv+8);
    float g = 0.f;
    #pragma unroll
    for (int i=0;i<16;i++) g += rv[i]*sW[i*256+j];
    s += us2f(m[(size_t)e*DEM + j])*g;
  }
  outp[(size_t)n*DEM + j] = s;
}

// ---------------- Ewald ----------------
__global__ void k_sf(const float* __restrict__ cosk, const float* __restrict__ sink_,
                     const float* __restrict__ h, const float* __restrict__ kf,
                     float* __restrict__ sfre, float* __restrict__ sfim){
  int bk = blockIdx.x; int b = bk>>5, k = bk&31;
  int a = threadIdx.x;
  float sre=0.f, sim=0.f;
  int n0 = b*APM;
  for (int i=0;i<APM;i++){
    float c = cosk[(n0+i)*NK+k];
    float s = sink_[(n0+i)*NK+k];
    float hv = h[(size_t)(n0+i)*DA+a];
    sre += c*hv; sim += s*hv;
  }
  float f = kf[k*DA+a];
  sfre[(size_t)bk*DA+a] = sre*f;
  sfim[(size_t)bk*DA+a] = sim*f;
}

__global__ void k_ew(const float* __restrict__ cosk, const float* __restrict__ sink_,
                     const float* __restrict__ sfre, const float* __restrict__ sfim,
                     float* __restrict__ ew){
  int n = blockIdx.x; int a = threadIdx.x; int b = n>>8;
  float s=0.f;
  for (int k=0;k<NK;k++){
    s += cosk[n*NK+k]*sfre[(size_t)(b*NK+k)*DA+a] + sink_[n*NK+k]*sfim[(size_t)(b*NK+k)*DA+a];
  }
  ew[(size_t)n*DA+a]=s;
}

// ---------------- fused h update ----------------
__global__ void __launch_bounds__(128)
k_hup(const float* __restrict__ hsum, const float* __restrict__ ewb,
      const float* __restrict__ Wat, const float* __restrict__ Wew,
      float* __restrict__ h){
  __shared__ float sA[16*256];
  __shared__ float sB[16*128];
  int row0 = blockIdx.x*16;
  int j = threadIdx.x;
  for (int idx=j; idx<4096; idx+=128) sA[idx] = hsum[(size_t)row0*DEM + idx];
  for (int idx=j; idx<2048; idx+=128) sB[idx] = ewb[(size_t)row0*DA + idx];
  __syncthreads();
  float a1[16], a2[16];
  #pragma unroll
  for (int i=0;i<16;i++){ a1[i]=0.f; a2[i]=0.f; }
  for (int k=0;k<256;k++){
    float w = Wat[k*DA+j];
    #pragma unroll
    for (int i=0;i<16;i++) a1[i] += sA[i*256+k]*w;
  }
  for (int k=0;k<128;k++){
    float w = Wew[k*DA+j];
    #pragma unroll
    for (int i=0;i<16;i++) a2[i] += sB[i*128+k]*w;
  }
  #pragma unroll
  for (int i=0;i<16;i++){
    size_t oi = (size_t)(row0+i)*DA + j;
    h[oi] = (h[oi] + silu_f(a1[i]) + silu_f(a2[i]))*0.5773502691896258f;
  }
}

// ---------------- output ----------------
__global__ void k_out_atom(const float* __restrict__ Ea, const float* __restrict__ W1,
                           const float* __restrict__ W2, float* __restrict__ atom_e){
  __shared__ float red[128];
  int n = blockIdx.x; int j = threadIdx.x;
  const float* row = Ea + (size_t)n*DEM;
  float s=0.f;
  for (int k=0;k<DEM;k++) s += row[k]*W1[k*DA+j];
  float v = silu_f(s)*W2[j];
  red[j]=v; __syncthreads();
  for (int st=64; st>0; st>>=1){ if (j<st) red[j]+=red[j+st]; __syncthreads(); }
  if (j==0) atom_e[n]=red[0];
}

__global__ void k_out_mol(const float* __restrict__ atom_e, float* __restrict__ out){
  __shared__ float red[256];
  int b = blockIdx.x; int t = threadIdx.x;
  red[t] = atom_e[b*APM+t]; __syncthreads();
  for (int st=128; st>0; st>>=1){ if (t<st) red[t]+=red[t+st]; __syncthreads(); }
  if (t==0) out[b]=red[0];
}

extern "C" void kernel_launch(void* const* d_in, const int* in_sizes, int n_in,
                              void* d_out, int out_size, void* d_ws, size_t ws_size,
                              hipStream_t stream){
  (void)in_sizes; (void)n_in; (void)out_size;
  const float* pos    = (const float*)d_in[0];
  const float* atab   = (const float*)d_in[1];
  const float* W_edge = (const float*)d_in[2];
  const float* b_edge = (const float*)d_in[3];
  const float* W_rbf3 = (const float*)d_in[4];
  const float* W_rbf3E= (const float*)d_in[5];
  const float* W_cbf3 = (const float*)d_in[6];
  const float* W_ba   = (const float*)d_in[7];
  const float* W_dt   = (const float*)d_in[8];
  const float* W_bil  = (const float*)d_in[9];
  const float* W_up   = (const float*)d_in[10];
  const float* W_r1   = (const float*)d_in[11];
  const float* W_r2   = (const float*)d_in[12];
  const float* W_rbfh = (const float*)d_in[13];
  const float* W_h    = (const float*)d_in[14];
  const float* W_atom = (const float*)d_in[15];
  const float* kgrid  = (const float*)d_in[16];
  const float* krbfv  = (const float*)d_in[17];
  const float* W_dk   = (const float*)d_in[18];
  const float* W_kf   = (const float*)d_in[19];
  const float* W_ewm  = (const float*)d_in[20];
  const float* W_cat  = (const float*)d_in[21];
  const float* W_rbfo = (const float*)d_in[22];
  const float* W_oute = (const float*)d_in[23];
  const float* W_o1   = (const float*)d_in[24];
  const float* W_o2   = (const float*)d_in[25];
  const int* z     = (const int*)d_in[26];
  const int* esrc  = (const int*)d_in[27];
  const int* etgt  = (const int*)d_in[28];
  const int* id3ba = (const int*)d_in[29];
  const int* id3ca = (const int*)d_in[30];
  float* out = (float*)d_out;

  // ---- workspace carve (bytes), ~221 MiB ----
  char* base = (char*)d_ws;
  size_t off = 0;
  auto alloc = [&](size_t bytes)->char*{
    char* p = base + off;
    off += (bytes + 255) & ~(size_t)255;
    return p;
  };
  u16*   m     = (u16*)  alloc((size_t)NE*DEM*2);     // 128 MiB (tgt-sorted edge order)
  float4* vecd = (float4*)alloc((size_t)NE*16);       // 4 MiB
  float* dlen  = (float*)alloc((size_t)NE*4);
  u16*   r16a  = (u16*)  alloc((size_t)NE*16*2);
  u16*   r16h  = (u16*)  alloc((size_t)NE*16*2);
  u16*   r16o  = (u16*)  alloc((size_t)NE*16*2);
  float* h     = (float*)alloc((size_t)NA*DA*4);
  float* cosk  = (float*)alloc((size_t)NA*NK*4);
  float* sinkb = (float*)alloc((size_t)NA*NK*4);
  float* sfre  = (float*)alloc((size_t)NB*NK*DA*4);
  float* sfim  = (float*)alloc((size_t)NB*NK*DA*4);
  float* kf    = (float*)alloc((size_t)NK*DA*4);
  float* atome = (float*)alloc((size_t)NA*4);
  char*  scr   = alloc((size_t)24*1024*1024);         // union region
  int* tgt_off = (int*)alloc((size_t)(NA+1)*4);
  int* tgt_list= (int*)alloc((size_t)NE*4);
  int* iperm   = (int*)alloc((size_t)NE*4);           // orig edge -> sorted pos
  int* esrc_p  = (int*)alloc((size_t)NE*4);
  int* etgt_p  = (int*)alloc((size_t)NE*4);
  int* ca_off  = (int*)alloc((size_t)(NE+1)*4);
  int* ca_list = (int*)alloc((size_t)NT*4);           // iperm[id3_ba] VALUES
  int* parts   = (int*)alloc((size_t)1024*4);
  // bf16 transposed weights
  u16* wt_edge = (u16*)alloc((size_t)256*384*2);
  u16* wt_ba   = (u16*)alloc((size_t)2*256*256*2);
  u16* wt_r3e  = (u16*)alloc((size_t)2*256*32*2);
  u16* wt_dt   = (u16*)alloc((size_t)2*32*256*2);
  u16* wt_up   = (u16*)alloc((size_t)2*256*64*2);
  u16* wt_r1   = (u16*)alloc((size_t)2*256*256*2);
  u16* wt_r2   = (u16*)alloc((size_t)2*256*256*2);
  u16* wt_cat  = (u16*)alloc((size_t)2*256*512*2);
  u16* wt_cbf  = (u16*)alloc((size_t)112*128*2);
  u16* wt_bil  = (u16*)alloc((size_t)2*64*512*2);
  u16* Ppre    = (u16*)alloc((size_t)NT*8*2);         // 16 MiB per-triplet Legendre (bf16)
  size_t need = off;
  if (ws_size < need) return;  // diagnostic: zero output => ws too small

  // scratch aliases
  u16*   xtrip = (u16*)scr;
  float* hsum  = (float*)scr;
  float* ewb   = (float*)(scr + (size_t)16*1024*1024);
  int* tmpi    = (int*)r16a;   // CSR temps (pre-phase, before r16 written)
  int* tgt_cnt = tmpi;
  int* tgt_loc = tmpi + NA;
  int* tgt_cur = tmpi + 2*NA;
  int* ca_cnt  = tmpi + 3*NA;
  int* ca_loc  = ca_cnt + NE;
  int* ca_cur  = ca_loc + NE;

  // ---- merged weight prep (bf16 W^T) ----
  WprepTable wt;
  int wn = 0;
  auto addw = [&](const float* src, u16* dst, int K, int N, int Kpad){
    wt.d[wn].src = src; wt.d[wn].dst = dst; wt.d[wn].K = K; wt.d[wn].N = N;
    wt.d[wn].Kpad = Kpad; wt.d[wn].elems = N*Kpad; wn++;
  };
  addw(W_edge, wt_edge, 384, 256, 384);
  for (int l=0; l<2; l++){
    addw(W_ba  + (size_t)l*256*256, wt_ba  + (size_t)l*256*256, 256, 256, 256);
    addw(W_rbf3E+(size_t)l*16*256,  wt_r3e + (size_t)l*256*32,  16,  256, 32);
    addw(W_dt  + (size_t)l*256*32,  wt_dt  + (size_t)l*32*256,  256, 32,  256);
    addw(W_up  + (size_t)l*64*256,  wt_up  + (size_t)l*256*64,  64,  256, 64);
    addw(W_r1  + (size_t)l*256*256, wt_r1  + (size_t)l*256*256, 256, 256, 256);
    addw(W_r2  + (size_t)l*256*256, wt_r2  + (size_t)l*256*256, 256, 256, 256);
    addw(W_cat + (size_t)l*512*256, wt_cat + (size_t)l*256*512, 512, 256, 512);
  }
  wt.n = wn;
  long long wtot = 0;
  for (int q=0;q<wn;q++) wtot += wt.d[q].elems;
  k_wprep_all<<<(int)((wtot+255)/256), 256, 0, stream>>>(wt);
  {
    WprepTable wb; int bn=0;
    auto addb = [&](const float* src, u16* dst, int K, int N, int Kpad){
      wb.d[bn].src=src; wb.d[bn].dst=dst; wb.d[bn].K=K; wb.d[bn].N=N;
      wb.d[bn].Kpad=Kpad; wb.d[bn].elems=N*Kpad; bn++;
    };
    addb(W_bil, wt_bil, 512, 64, 512);
    addb(W_bil + (size_t)512*64, wt_bil + (size_t)64*512, 512, 64, 512);
    wb.n = bn;
    long long btot = 0;
    for (int q=0;q<bn;q++) btot += wb.d[q].elems;
    k_wprep_all<<<(int)((btot+255)/256), 256, 0, stream>>>(wb);
  }
  k_wprep_cbf<<<(112*128+255)/256, 256, 0, stream>>>(W_cbf3, wt_cbf);

  // ---- CSR: edge_tgt -> atoms (gives tgt-sorted edge permutation) ----
  k_zero<<<NA/256, 256, 0, stream>>>(tgt_cnt, NA);
  k_count<<<NE/256, 256, 0, stream>>>(etgt, NE, tgt_cnt);
  k_scan1<<<NA/256, 256, 0, stream>>>(tgt_cnt, NA, tgt_loc, parts);
  k_scan2<<<1, 256, 0, stream>>>(parts, NA/256);
  k_scan3<<<NA/256, 256, 0, stream>>>(tgt_loc, parts, tgt_cnt, NA, tgt_off);
  k_copy_int<<<NA/256, 256, 0, stream>>>(tgt_off, NA, tgt_cur);
  k_fill<<<NE/256, 256, 0, stream>>>(etgt, NE, tgt_cur, tgt_list);
  k_iperm<<<NE/256, 256, 0, stream>>>(tgt_list, NE, iperm);
  k_permute2<<<NE/256, 256, 0, stream>>>(tgt_list, esrc, etgt, NE, esrc_p, etgt_p);

  // ---- geometry in permuted edge space ----
  k_geom<<<NE/256, 256, 0, stream>>>(pos, esrc_p, etgt_p, vecd, dlen);

  // ---- CSR: id3_ca -> permuted edges (values = iperm[id3_ba], P precompute) ----
  k_zero<<<NE/256, 256, 0, stream>>>(ca_cnt, NE);
  k_count_map<<<NT/256, 256, 0, stream>>>(id3ca, iperm, NT, ca_cnt);
  k_scan1<<<NE/256, 256, 0, stream>>>(ca_cnt, NE, ca_loc, parts);
  k_scan2<<<1, 256, 0, stream>>>(parts, NE/256);
  k_scan3<<<NE/256, 256, 0, stream>>>(ca_loc, parts, ca_cnt, NE, ca_off);
  k_copy_int<<<NE/256, 256, 0, stream>>>(ca_off, NE, ca_cur);
  k_fill_valmap_P<<<NT/256, 256, 0, stream>>>(id3ca, id3ba, iperm, vecd, NT,
                                              ca_cur, ca_list, Ppre);

  // ---- bases ----
  k_rbf16<<<NE/4, 256, 0, stream>>>(dlen, W_rbf3, W_rbfh, W_rbfo, r16a, r16h, r16o);
  k_gather_h<<<NA*DA/256, 256, 0, stream>>>(atab, z, h);
  k_kdot<<<NA*NK/256, 256, 0, stream>>>(pos, kgrid, cosk, sinkb);
  k_kf<<<1, 256, 0, stream>>>(krbfv, W_dk, W_kf, kf);
  k_edgeinit_mx<<<NE/64, 256, 0, stream>>>(h, dlen, wt_edge, b_edge, esrc_p, etgt_p, m);

  // ---- interaction blocks ----
  for (int l=0; l<2; l++){
    k_ba_dt_mx<<<NE/32, 256, 0, stream>>>(m, wt_ba + (size_t)l*256*256,
                                          r16a, wt_r3e + (size_t)l*256*32,
                                          wt_dt + (size_t)l*32*256, xtrip);
    k_trip<<<NE/16, 256, 0, stream>>>(ca_off, ca_list, Ppre, dlen, wt_cbf,
                                      xtrip, wt_bil + (size_t)l*64*512,
                                      wt_up + (size_t)l*256*64, m);
    k_res_mx<<<NE/64, 256, 0, stream>>>(wt_r1 + (size_t)l*256*256,
                                        wt_r2 + (size_t)l*256*256, m);
    k_gseg_seq<<<NA, 256, 0, stream>>>(tgt_off, m, r16h, W_h + (size_t)l*16*DEM, hsum);
    k_sf<<<NB*NK, 128, 0, stream>>>(cosk, sinkb, h, kf, sfre, sfim);
    k_ew<<<NA, 128, 0, stream>>>(cosk, sinkb, sfre, sfim, ewb);
    k_hup<<<NA/16, 128, 0, stream>>>(hsum, ewb, W_atom + (size_t)l*DEM*DA,
                                     W_ewm + (size_t)l*DA*DA, h);
    k_catref_mx<<<NE/64, 256, 0, stream>>>(h, wt_cat + (size_t)l*256*512, esrc_p, etgt_p, m);
  }

  // ---- output ----
  k_gseg_seq<<<NA, 256, 0, stream>>>(tgt_off, m, r16o, W_oute, hsum);
  k_out_atom<<<NA, 128, 0, stream>>>(hsum, W_o1, W_o2, atome);
  k_out_mol<<<NB, 256, 0, stream>>>(atome, out);
}

// Round 20
// 3683.923 us; speedup vs baseline: 1.0105x; 1.0105x over previous
//
#include <hip/hip_runtime.h>
#include <math.h>

#define NA 16384
#define NB 64
#define NE 262144
#define NT 1048576
#define NR 128
#define DA 128
#define DEM 256
#define DTR 32
#define DC 16
#define DBIL 64
#define DNKR 128
#define DDP 8
#define NK 32
#define APM 256
#define PI_F 3.14159265358979323846f

typedef unsigned short u16;
typedef unsigned int u32;
typedef __attribute__((ext_vector_type(8))) short bf16x8;
typedef __attribute__((ext_vector_type(4))) float f32x4;

__device__ __forceinline__ float silu_f(float x){ return x / (1.0f + __expf(-x)); }
__device__ __forceinline__ float us2f(u32 u){ return __uint_as_float(u<<16); }
__device__ __forceinline__ u16 f2us(float f){
  u32 x = __float_as_uint(f);
  u32 r = x + 0x7fffu + ((x>>16)&1u);
  return (u16)(r>>16);
}
__device__ __forceinline__ void unp8(uint4 v, float* o){
  o[0]=us2f(v.x&0xffffu); o[1]=us2f(v.x>>16);
  o[2]=us2f(v.y&0xffffu); o[3]=us2f(v.y>>16);
  o[4]=us2f(v.z&0xffffu); o[5]=us2f(v.z>>16);
  o[6]=us2f(v.w&0xffffu); o[7]=us2f(v.w>>16);
}
__device__ __forceinline__ uint4 pack8(const float* v){
  uint4 r;
  r.x = (u32)f2us(v[0]) | ((u32)f2us(v[1])<<16);
  r.y = (u32)f2us(v[2]) | ((u32)f2us(v[3])<<16);
  r.z = (u32)f2us(v[4]) | ((u32)f2us(v[5])<<16);
  r.w = (u32)f2us(v[6]) | ((u32)f2us(v[7])<<16);
  return r;
}
__device__ __forceinline__ float rbf_val(float d, int r){
  float ds = d*(1.0f/6.0f);
  float env = 0.0f;
  if (ds < 1.0f){
    float p2 = ds*ds, p5 = p2*p2*ds;
    env = 1.0f - 21.0f*p5 + 35.0f*p5*ds - 15.0f*p5*p2;
  }
  return env * 0.5773502691896258f * __sinf((float)(r+1)*PI_F*ds) / d;
}

// ---- swizzled bf16 LDS tile helpers (16B slot index ^= row&7) ----
__device__ __forceinline__ bf16x8 ldsA(const u16* sA, int row, int KLD, int slot){
  int s = slot ^ (row&7);
  return *(const bf16x8*)(sA + row*KLD + s*8);
}
__device__ __forceinline__ void stSlot(u16* sA, int row, int KLD, int slot, uint4 v){
  int s = slot ^ (row&7);
  *(uint4*)(sA + row*KLD + s*8) = v;
}
__device__ __forceinline__ void stW(u16* sA, int row, int KLD, int col, u16 v){
  int s = (col>>3) ^ (row&7);
  sA[row*KLD + s*8 + (col&7)] = v;
}
__device__ __forceinline__ bf16x8 ldB(const u16* Wt, int col, int K, int koff){
  return *(const bf16x8*)(Wt + (size_t)col*K + koff);
}

// ---------------- utility ----------------
__global__ void k_zero(int* __restrict__ p, int n){
  int i = blockIdx.x*256+threadIdx.x; if (i<n) p[i]=0;
}

// ---------------- merged weight prep: fp32 [K][N] -> bf16 [N][Kpad] ----------------
struct WprepDesc { const float* src; u16* dst; int K; int N; int Kpad; int elems; };
struct WprepTable { WprepDesc d[15]; int n; };
__global__ void k_wprep_all(WprepTable t){
  long long i = (long long)blockIdx.x*256 + threadIdx.x;
  for (int q=0;q<15;q++){
    if (q >= t.n) return;
    int e = t.d[q].elems;
    if (i < e){
      int Kpad = t.d[q].Kpad;
      int n = (int)(i / Kpad), k = (int)(i - (long long)n*Kpad);
      t.d[q].dst[(size_t)n*Kpad + k] =
        (k < t.d[q].K)? f2us(t.d[q].src[(size_t)k*t.d[q].N + n]) : (u16)0;
      return;
    }
    i -= e;
  }
}
__global__ void k_wprep_cbf(const float* __restrict__ src, u16* __restrict__ dst){
  int i = blockIdx.x*256+threadIdx.x;
  if (i >= 112*128) return;
  int n = i>>7, k = i&127;
  int s = n>>4, c = n&15;
  dst[i] = f2us(src[s*2048 + k*16 + c]);
}

// ---------------- permutation helpers ----------------
__global__ void k_iperm(const int* __restrict__ list, int n, int* __restrict__ iperm){
  int i = blockIdx.x*256+threadIdx.x;
  if (i<n) iperm[list[i]] = i;
}
__global__ void k_permute2(const int* __restrict__ list, const int* __restrict__ a,
                           const int* __restrict__ b, int n,
                           int* __restrict__ ap, int* __restrict__ bp){
  int i = blockIdx.x*256+threadIdx.x;
  if (i<n){ int e = list[i]; ap[i]=a[e]; bp[i]=b[e]; }
}
__global__ void k_count_map(const int* __restrict__ ids, const int* __restrict__ map,
                            int num, int* __restrict__ cnt){
  int i = blockIdx.x*256+threadIdx.x;
  if (i<num) atomicAdd(&cnt[map[ids[i]]],1);
}
__global__ void k_fill_valmap(const int* __restrict__ ids, const int* __restrict__ vals,
                              const int* __restrict__ map, int num,
                              int* __restrict__ cur, int* __restrict__ list){
  int i = blockIdx.x*256+threadIdx.x;
  if (i<num){ int p = atomicAdd(&cur[map[ids[i]]],1); list[p]=map[vals[i]]; }
}

// ---------------- geometry (permuted edge order): vec + 1/d ----------------
__global__ void k_geom(const float* __restrict__ pos, const int* __restrict__ src,
                       const int* __restrict__ tgt, float4* __restrict__ vecd,
                       float* __restrict__ dlen){
  int e = blockIdx.x*256+threadIdx.x;
  if (e >= NE) return;
  int s = src[e], t = tgt[e];
  float vx = pos[s*3+0]-pos[t*3+0];
  float vy = pos[s*3+1]-pos[t*3+1];
  float vz = pos[s*3+2]-pos[t*3+2];
  float d = sqrtf(vx*vx+vy*vy+vz*vz + 1e-12f);
  vecd[e] = make_float4(vx,vy,vz,1.0f/d);
  dlen[e] = d;
}

// ---------------- r16a/h/o (bf16 out) ----------------
__global__ void __launch_bounds__(256)
k_rbf16(const float* __restrict__ dlen, const float* __restrict__ W1,
        const float* __restrict__ W2, const float* __restrict__ W3,
        u16* __restrict__ r16a, u16* __restrict__ r16h, u16* __restrict__ r16o){
  __shared__ float rb[4*128];
  int e0 = blockIdx.x*4;
  int tid = threadIdx.x, eg = tid>>6, lt = tid&63;
  int e = e0+eg;
  float d = dlen[e];
  rb[eg*128+lt]    = rbf_val(d, lt);
  rb[eg*128+lt+64] = rbf_val(d, lt+64);
  __syncthreads();
  if (lt < 48){
    int which = lt>>4, jj = lt&15;
    const float* W = (which==0)? W1 : (which==1)? W2 : W3;
    float acc=0.f;
    for (int r=0;r<NR;r++) acc += rb[eg*128+r]*W[r*16+jj];
    u16* o = (which==0)? r16a : (which==1)? r16h : r16o;
    o[(size_t)e*16+jj] = f2us(acc);
  }
}

// ---------------- h = atom_table[z] ----------------
__global__ void k_gather_h(const float* __restrict__ table, const int* __restrict__ z,
                           float* __restrict__ h){
  int idx = blockIdx.x*256 + threadIdx.x;
  int n = idx >> 7, a = idx & 127;
  h[idx] = table[z[n]*DA + a];
}

// ---------------- kdot cos/sin ----------------
__global__ void k_kdot(const float* __restrict__ pos, const float* __restrict__ kg,
                       float* __restrict__ cosk, float* __restrict__ sink_){
  int idx = blockIdx.x*256+threadIdx.x;
  int n = idx>>5, k = idx&31;
  float dotv = pos[n*3]*kg[k*3]+pos[n*3+1]*kg[k*3+1]+pos[n*3+2]*kg[k*3+2];
  float s, c;
  sincosf(dotv, &s, &c);
  cosk[idx] = c; sink_[idx] = s;
}

// ---------------- kf ----------------
__global__ void k_kf(const float* __restrict__ krbf, const float* __restrict__ Wd,
                     const float* __restrict__ Wf, float* __restrict__ kf){
  __shared__ float t[NK*DDP];
  int tid = threadIdx.x;
  { int k = tid>>3, d = tid&7;
    float s=0.f;
    for (int r=0;r<DNKR;r++) s += krbf[k*DNKR+r]*Wd[r*DDP+d];
    t[tid] = silu_f(s); }
  __syncthreads();
  for (int idx=tid; idx<NK*DA; idx+=256){
    int k = idx>>7, a = idx&127;
    float s=0.f;
    #pragma unroll
    for (int d=0; d<DDP; d++) s += t[k*DDP+d]*Wf[d*DA+a];
    kf[idx]=s;
  }
}

// ---------------- CSR build ----------------
__global__ void k_count(const int* __restrict__ ids, int num, int* __restrict__ cnt){
  int i = blockIdx.x*256+threadIdx.x;
  if (i<num) atomicAdd(&cnt[ids[i]],1);
}
__global__ void k_scan1(const int* __restrict__ cnt, int n, int* __restrict__ loc,
                        int* __restrict__ part){
  __shared__ int lds[256];
  int i = blockIdx.x*256+threadIdx.x;
  int v = (i<n)?cnt[i]:0;
  lds[threadIdx.x]=v; __syncthreads();
  for (int off=1; off<256; off<<=1){
    int tv = (threadIdx.x >= (unsigned)off)? lds[threadIdx.x-off]:0;
    __syncthreads();
    lds[threadIdx.x]+=tv;
    __syncthreads();
  }
  if (i<n) loc[i] = lds[threadIdx.x]-v;
  if (threadIdx.x==255) part[blockIdx.x]=lds[255];
}
__global__ void k_scan2(int* __restrict__ part, int nparts){
  __shared__ int lds[1024];
  int tid=threadIdx.x;
  for (int i=tid;i<1024;i+=256) lds[i] = (i<nparts)? part[i] : 0;
  __syncthreads();
  if (tid==0){
    int run=0;
    for (int i=0;i<nparts;i++){ int v=lds[i]; lds[i]=run; run+=v; }
  }
  __syncthreads();
  for (int i=tid;i<1024;i+=256) if (i<nparts) part[i]=lds[i];
}
__global__ void k_scan3(const int* __restrict__ loc, const int* __restrict__ part,
                        const int* __restrict__ cnt, int n, int* __restrict__ off){
  int i = blockIdx.x*256+threadIdx.x;
  if (i<n){ int o = loc[i]+part[i>>8]; off[i]=o; if (i==n-1) off[n]=o+cnt[i]; }
}
__global__ void k_copy_int(const int* __restrict__ a, int n, int* __restrict__ b){
  int i=blockIdx.x*256+threadIdx.x; if(i<n) b[i]=a[i];
}
__global__ void k_fill(const int* __restrict__ ids, int num, int* __restrict__ cur,
                       int* __restrict__ list){
  int i = blockIdx.x*256+threadIdx.x;
  if (i<num){ int p = atomicAdd(&cur[ids[i]],1); list[p]=i; }
}

// ================= MFMA edge-GEMM family =================

// ---------------- initial edge embedding (K=384, phased 256+128) ----------------
__global__ void __launch_bounds__(256)
k_edgeinit_mx(const float* __restrict__ h, const float* __restrict__ dlen,
              const u16* __restrict__ Wt, const float* __restrict__ bias,
              const int* __restrict__ src, const int* __restrict__ tgt,
              u16* __restrict__ outm){
  __shared__ u16 sA[64*256];   // 32 KB
  int e0 = blockIdx.x*64;
  int j = threadIdx.x, lane = j&63, w = j>>6;
  int rbase = (w&1)*32, cbase = (w>>1)*128;
  int l15 = lane&15, kg = lane>>4;
  f32x4 acc[2][8];
  #pragma unroll
  for (int rt=0;rt<2;rt++)
    #pragma unroll
    for (int i=0;i<8;i++) acc[rt][i] = (f32x4){0.f,0.f,0.f,0.f};
  for (int idx=j; idx<64*32; idx+=256){
    int row = idx>>5, slot = idx&31;
    int e = e0+row;
    const float* srcp = (slot<16)? (h + (size_t)src[e]*DA + slot*8)
                                 : (h + (size_t)tgt[e]*DA + (slot-16)*8);
    float v[8];
    float4 q0 = *(const float4*)srcp, q1 = *(const float4*)(srcp+4);
    v[0]=q0.x; v[1]=q0.y; v[2]=q0.z; v[3]=q0.w;
    v[4]=q1.x; v[5]=q1.y; v[6]=q1.z; v[7]=q1.w;
    stSlot(sA, row, 256, slot, pack8(v));
  }
  __syncthreads();
  #pragma unroll 2
  for (int kc=0; kc<8; kc++){
    bf16x8 a0 = ldsA(sA, rbase+l15,    256, kc*4+kg);
    bf16x8 a1 = ldsA(sA, rbase+16+l15, 256, kc*4+kg);
    #pragma unroll
    for (int ct=0; ct<8; ct++){
      bf16x8 b = ldB(Wt, cbase+ct*16+l15, 384, kc*32+kg*8);
      acc[0][ct] = __builtin_amdgcn_mfma_f32_16x16x32_bf16(a0, b, acc[0][ct], 0,0,0);
      acc[1][ct] = __builtin_amdgcn_mfma_f32_16x16x32_bf16(a1, b, acc[1][ct], 0,0,0);
    }
  }
  __syncthreads();
  for (int idx=j; idx<64*16; idx+=256){
    int row = idx>>4, slot = idx&15;
    float dv = dlen[e0+row];
    float v[8];
    #pragma unroll
    for (int q=0;q<8;q++) v[q] = rbf_val(dv, slot*8+q);
    stSlot(sA, row, 256, slot, pack8(v));
  }
  __syncthreads();
  #pragma unroll 2
  for (int kc=8; kc<12; kc++){
    bf16x8 a0 = ldsA(sA, rbase+l15,    256, (kc-8)*4+kg);
    bf16x8 a1 = ldsA(sA, rbase+16+l15, 256, (kc-8)*4+kg);
    #pragma unroll
    for (int ct=0; ct<8; ct++){
      bf16x8 b = ldB(Wt, cbase+ct*16+l15, 384, kc*32+kg*8);
      acc[0][ct] = __builtin_amdgcn_mfma_f32_16x16x32_bf16(a0, b, acc[0][ct], 0,0,0);
      acc[1][ct] = __builtin_amdgcn_mfma_f32_16x16x32_bf16(a1, b, acc[1][ct], 0,0,0);
    }
  }
  #pragma unroll
  for (int rt=0;rt<2;rt++)
  #pragma unroll
  for (int ct=0; ct<8; ct++){
    int col = cbase + ct*16 + l15;
    float bv = bias[col];
    #pragma unroll
    for (int r=0;r<4;r++){
      int row = rbase + rt*16 + kg*4 + r;
      outm[(size_t)(e0+row)*DEM + col] = f2us(silu_f(acc[rt][ct][r] + bv));
    }
  }
}

// ---- fused: T1=silu(m@W_ba)*(r16@W_r3e); xtrip=silu(T1@W_dt)  (32 rows) ----
__global__ void __launch_bounds__(256)
k_ba_dt_mx(const u16* __restrict__ m, const u16* __restrict__ WtBA,
           const u16* __restrict__ r16, const u16* __restrict__ WtR3E,
           const u16* __restrict__ WtDT, u16* __restrict__ xtrip){
  __shared__ u16 sM[32*256];
  __shared__ u16 sR[32*64];
  int e0 = blockIdx.x*32;
  int j = threadIdx.x, lane = j&63, w = j>>6;
  for (int p=j; p<32*32; p+=256){
    int row = p>>5, slot = p&31;
    uint4 v = *(const uint4*)(m + (size_t)(e0+row)*DEM + slot*8);
    stSlot(sM, row, 256, slot, v);
  }
  for (int p=j; p<32*8; p+=256){
    int row = p>>3, slot = p&7;
    uint4 v = {0u,0u,0u,0u};
    if (slot<2) v = *(const uint4*)(r16 + (size_t)(e0+row)*16 + slot*8);
    stSlot(sR, row, 64, slot, v);
  }
  __syncthreads();
  int rbase = (w&1)*16, cbase = (w>>1)*128;
  int l15 = lane&15, kg = lane>>4;
  int arow = rbase + l15;
  f32x4 accA[8], accG[8];
  #pragma unroll
  for (int i=0;i<8;i++){ accA[i]=(f32x4){0.f,0.f,0.f,0.f}; accG[i]=(f32x4){0.f,0.f,0.f,0.f}; }
  #pragma unroll 2
  for (int kc=0; kc<8; kc++){
    bf16x8 a = ldsA(sM, arow, 256, kc*4+kg);
    #pragma unroll
    for (int ct=0; ct<8; ct++){
      bf16x8 b = ldB(WtBA, cbase+ct*16+l15, 256, kc*32+kg*8);
      accA[ct] = __builtin_amdgcn_mfma_f32_16x16x32_bf16(a, b, accA[ct], 0,0,0);
    }
  }
  { bf16x8 a = ldsA(sR, arow, 64, kg);
    #pragma unroll
    for (int ct=0; ct<8; ct++){
      bf16x8 b = ldB(WtR3E, cbase+ct*16+l15, 32, kg*8);
      accG[ct] = __builtin_amdgcn_mfma_f32_16x16x32_bf16(a, b, accG[ct], 0,0,0);
    } }
  __syncthreads();
  #pragma unroll
  for (int ct=0; ct<8; ct++){
    int col = cbase + ct*16 + l15;
    #pragma unroll
    for (int r=0;r<4;r++){
      int row = rbase + kg*4 + r;
      stW(sM, row, 256, col, f2us(silu_f(accA[ct][r])*accG[ct][r]));
    }
  }
  __syncthreads();
  int rb2 = (w&1)*16, ct2 = (w>>1);
  int arow2 = rb2 + l15;
  f32x4 acc2 = (f32x4){0.f,0.f,0.f,0.f};
  #pragma unroll 2
  for (int kc=0; kc<8; kc++){
    bf16x8 a = ldsA(sM, arow2, 256, kc*4+kg);
    bf16x8 b = ldB(WtDT, ct2*16+l15, 256, kc*32+kg*8);
    acc2 = __builtin_amdgcn_mfma_f32_16x16x32_bf16(a, b, acc2, 0,0,0);
  }
  #pragma unroll
  for (int r=0;r<4;r++){
    int row = rb2 + kg*4 + r;
    int col = ct2*16 + l15;
    xtrip[(size_t)(e0+row)*DTR + col] = f2us(silu_f(acc2[r]));
  }
}

// ---------------- triplet bilinear + fused W_up m-update (single-chain, bf16 rW) ----------------
__global__ void __launch_bounds__(256)
k_trip(const int* __restrict__ ca_off, const int* __restrict__ ba_list,
       const float4* __restrict__ vecd, const float* __restrict__ dlen,
       const u16* __restrict__ WtCBF, const u16* __restrict__ xtrip,
       const u16* __restrict__ WtBIL, const u16* __restrict__ WtUP,
       u16* __restrict__ m){
  __shared__ u16 sS3[16*512];    // 16 KB
  __shared__ u16 sRB[16*128];    // 4 KB
  __shared__ u16 rWl[16*112];    // 3.5 KB (bf16) -> 26.1 KB total, 6 blocks/CU
  __shared__ u16 sX3[16*64];     // 2 KB
  int e0 = blockIdx.x*16;
  int tid = threadIdx.x, lane = tid&63, w = tid>>6;
  int l15 = lane&15, kg = lane>>4;
  for (int idx=tid; idx<2048; idx+=256){
    int e = idx>>7, r = idx&127;
    stW(sRB, e, 128, r, f2us(rbf_val(dlen[e0+e], r)));
  }
  __syncthreads();
  for (int ct=w; ct<7; ct+=4){
    f32x4 acc = (f32x4){0.f,0.f,0.f,0.f};
    for (int kc=0; kc<4; kc++){
      bf16x8 a = ldsA(sRB, l15, 128, kc*4+kg);
      bf16x8 b = ldB(WtCBF, ct*16+l15, 128, kc*32+kg*8);
      acc = __builtin_amdgcn_mfma_f32_16x16x32_bf16(a, b, acc, 0,0,0);
    }
    #pragma unroll
    for (int r=0;r<4;r++)
      rWl[(kg*4+r)*112 + ct*16 + l15] = f2us(acc[r]);
  }
  __syncthreads();
  int half = lane>>5, tr = lane&31;
  for (int sub=0; sub<4; sub++){
    int el = w*4+sub, e = e0+el;
    float4 vd = vecd[e];           // vd.w = 1/d
    float a0=0.f,a1=0.f,a2=0.f,a3=0.f,a4=0.f,a5=0.f,a6=0.f;
    int beg = ca_off[e], end = ca_off[e+1];
    int cnt = end - beg;
    int c0 = (cnt+1)>>1;
    int mybeg = beg + half*c0;
    int myend = half ? end : beg+c0;
    float4 bd = make_float4(0.f,0.f,0.f,1.f);
    float xk = 0.f;
    if (mybeg<myend){
      int b0 = ba_list[mybeg];
      bd = vecd[b0];
      xk = us2f(xtrip[(size_t)b0*DTR + tr]);
    }
    for (int ti=mybeg; ti<myend; ti++){
      int bn = (ti+1<myend)? ba_list[ti+1] : 0;
      float4 bd_n = vecd[bn];
      float xk_n = us2f(xtrip[(size_t)bn*DTR + tr]);
      float x = (vd.x*bd.x + vd.y*bd.y + vd.z*bd.z)*vd.w*bd.w;
      x = fminf(1.0f, fmaxf(-1.0f, x));
      float p2 = (3.f*x*x - 1.f)*0.5f;
      float p3 = (5.f*x*p2 - 2.f*x)*(1.0f/3.0f);
      float p4 = (7.f*x*p3 - 3.f*p2)*0.25f;
      float p5 = (9.f*x*p4 - 4.f*p3)*0.2f;
      float p6 = (11.f*x*p5 - 5.f*p4)*(1.0f/6.0f);
      a0 += xk;    a1 += x*xk;  a2 += p2*xk; a3 += p3*xk;
      a4 += p4*xk; a5 += p5*xk; a6 += p6*xk;
      bd = bd_n; xk = xk_n;
    }
    a0 += __shfl_xor(a0, 32); a1 += __shfl_xor(a1, 32);
    a2 += __shfl_xor(a2, 32); a3 += __shfl_xor(a3, 32);
    a4 += __shfl_xor(a4, 32); a5 += __shfl_xor(a5, 32);
    a6 += __shfl_xor(a6, 32);
    const u16* rwe = rWl + el*112;
    #pragma unroll
    for (int q=0;q<8;q++){
      int c = half*8+q;
      float s3 = us2f(rwe[c])*a0 + us2f(rwe[16+c])*a1 + us2f(rwe[32+c])*a2
               + us2f(rwe[48+c])*a3 + us2f(rwe[64+c])*a4 + us2f(rwe[80+c])*a5
               + us2f(rwe[96+c])*a6;
      stW(sS3, el, 512, c*32+tr, f2us(s3));
    }
  }
  __syncthreads();
  { f32x4 acc = (f32x4){0.f,0.f,0.f,0.f};
    #pragma unroll 2
    for (int kc=0; kc<16; kc++){
      bf16x8 a = ldsA(sS3, l15, 512, kc*4+kg);
      bf16x8 b = ldB(WtBIL, w*16+l15, 512, kc*32+kg*8);
      acc = __builtin_amdgcn_mfma_f32_16x16x32_bf16(a, b, acc, 0,0,0);
    }
    #pragma unroll
    for (int r=0;r<4;r++)
      stW(sX3, kg*4+r, 64, w*16+l15, f2us(acc[r]));
  }
  __syncthreads();
  f32x4 acc2[4];
  #pragma unroll
  for (int i=0;i<4;i++) acc2[i] = (f32x4){0.f,0.f,0.f,0.f};
  for (int kc=0; kc<2; kc++){
    bf16x8 a = ldsA(sX3, l15, 64, kc*4+kg);
    #pragma unroll
    for (int ct=0; ct<4; ct++){
      bf16x8 b = ldB(WtUP, w*64+ct*16+l15, 64, kc*32+kg*8);
      acc2[ct] = __builtin_amdgcn_mfma_f32_16x16x32_bf16(a, b, acc2[ct], 0,0,0);
    }
  }
  #pragma unroll
  for (int ct=0; ct<4; ct++){
    int col = w*64 + ct*16 + l15;
    #pragma unroll
    for (int r=0;r<4;r++){
      int row = kg*4 + r;
      size_t oi = (size_t)(e0+row)*DEM + col;
      m[oi] = f2us((us2f(m[oi]) + silu_f(acc2[ct][r]))*0.7071067811865476f);
    }
  }
}

// ---------------- fused residual MLP (64 rows, 32KB shared buffer) ----------------
__global__ void __launch_bounds__(256)
k_res_mx(const u16* __restrict__ WtR1, const u16* __restrict__ WtR2, u16* __restrict__ m){
  __shared__ u16 sM[64*256];   // 32 KB (m, then overwritten by T1)
  int e0 = blockIdx.x*64;
  int j = threadIdx.x, lane = j&63, w = j>>6;
  for (int p=j; p<64*32; p+=256){
    int row = p>>5, slot = p&31;
    uint4 v = *(const uint4*)(m + (size_t)(e0+row)*DEM + slot*8);
    stSlot(sM, row, 256, slot, v);
  }
  __syncthreads();
  int rbase = (w&1)*32, cbase = (w>>1)*128;
  int l15 = lane&15, kg = lane>>4;
  f32x4 acc[2][8];
  #pragma unroll
  for (int rt=0;rt<2;rt++)
    #pragma unroll
    for (int i=0;i<8;i++) acc[rt][i]=(f32x4){0.f,0.f,0.f,0.f};
  #pragma unroll 2
  for (int kc=0; kc<8; kc++){
    bf16x8 a0 = ldsA(sM, rbase+l15,    256, kc*4+kg);
    bf16x8 a1 = ldsA(sM, rbase+16+l15, 256, kc*4+kg);
    #pragma unroll
    for (int ct=0; ct<8; ct++){
      bf16x8 b = ldB(WtR1, cbase+ct*16+l15, 256, kc*32+kg*8);
      acc[0][ct] = __builtin_amdgcn_mfma_f32_16x16x32_bf16(a0, b, acc[0][ct], 0,0,0);
      acc[1][ct] = __builtin_amdgcn_mfma_f32_16x16x32_bf16(a1, b, acc[1][ct], 0,0,0);
    }
  }
  __syncthreads();   // all reads of sM done -> safe to overwrite with T1
  #pragma unroll
  for (int rt=0;rt<2;rt++)
  #pragma unroll
  for (int ct=0; ct<8; ct++){
    int col = cbase + ct*16 + l15;
    #pragma unroll
    for (int r=0;r<4;r++)
      stW(sM, rbase + rt*16 + kg*4 + r, 256, col, f2us(silu_f(acc[rt][ct][r])));
  }
  __syncthreads();
  #pragma unroll
  for (int rt=0;rt<2;rt++)
    #pragma unroll
    for (int i=0;i<8;i++) acc[rt][i]=(f32x4){0.f,0.f,0.f,0.f};
  #pragma unroll 2
  for (int kc=0; kc<8; kc++){
    bf16x8 a0 = ldsA(sM, rbase+l15,    256, kc*4+kg);
    bf16x8 a1 = ldsA(sM, rbase+16+l15, 256, kc*4+kg);
    #pragma unroll
    for (int ct=0; ct<8; ct++){
      bf16x8 b = ldB(WtR2, cbase+ct*16+l15, 256, kc*32+kg*8);
      acc[0][ct] = __builtin_amdgcn_mfma_f32_16x16x32_bf16(a0, b, acc[0][ct], 0,0,0);
      acc[1][ct] = __builtin_amdgcn_mfma_f32_16x16x32_bf16(a1, b, acc[1][ct], 0,0,0);
    }
  }
  // residual re-read from global bf16 m (bit-identical to the staged copy)
  #pragma unroll
  for (int rt=0;rt<2;rt++)
  #pragma unroll
  for (int ct=0; ct<8; ct++){
    int col = cbase + ct*16 + l15;
    #pragma unroll
    for (int r=0;r<4;r++){
      int row = rbase + rt*16 + kg*4 + r;
      size_t oi = (size_t)(e0+row)*DEM + col;
      float orig = us2f(m[oi]);
      m[oi] = f2us((orig + silu_f(acc[rt][ct][r]))*0.7071067811865476f);
    }
  }
}

// ---------------- edge refresh (64 rows, K=512 phased 256+256, 32KB) ----------------
__global__ void __launch_bounds__(256)
k_catref_mx(const float* __restrict__ h, const u16* __restrict__ Wt,
            const int* __restrict__ src, const int* __restrict__ tgt,
            u16* __restrict__ m){
  __shared__ u16 sA[64*256];   // 32 KB
  int e0 = blockIdx.x*64;
  int j = threadIdx.x, lane = j&63, w = j>>6;
  int rbase = (w&1)*32, cbase = (w>>1)*128;
  int l15 = lane&15, kg = lane>>4;
  f32x4 acc[2][8];
  #pragma unroll
  for (int rt=0;rt<2;rt++)
    #pragma unroll
    for (int i=0;i<8;i++) acc[rt][i]=(f32x4){0.f,0.f,0.f,0.f};
  for (int idx=j; idx<64*32; idx+=256){
    int row = idx>>5, slot = idx&31;
    int e = e0+row;
    const float* srcp = (slot<16)? (h + (size_t)src[e]*DA + slot*8)
                                 : (h + (size_t)tgt[e]*DA + (slot-16)*8);
    float v[8];
    float4 q0 = *(const float4*)srcp, q1 = *(const float4*)(srcp+4);
    v[0]=q0.x; v[1]=q0.y; v[2]=q0.z; v[3]=q0.w;
    v[4]=q1.x; v[5]=q1.y; v[6]=q1.z; v[7]=q1.w;
    stSlot(sA, row, 256, slot, pack8(v));
  }
  __syncthreads();
  #pragma unroll 2
  for (int kc=0; kc<8; kc++){
    bf16x8 a0 = ldsA(sA, rbase+l15,    256, kc*4+kg);
    bf16x8 a1 = ldsA(sA, rbase+16+l15, 256, kc*4+kg);
    #pragma unroll
    for (int ct=0; ct<8; ct++){
      bf16x8 b = ldB(Wt, cbase+ct*16+l15, 512, kc*32+kg*8);
      acc[0][ct] = __builtin_amdgcn_mfma_f32_16x16x32_bf16(a0, b, acc[0][ct], 0,0,0);
      acc[1][ct] = __builtin_amdgcn_mfma_f32_16x16x32_bf16(a1, b, acc[1][ct], 0,0,0);
    }
  }
  __syncthreads();
  for (int p=j; p<64*32; p+=256){
    int row = p>>5, slot = p&31;
    uint4 v = *(const uint4*)(m + (size_t)(e0+row)*DEM + slot*8);
    stSlot(sA, row, 256, slot, v);
  }
  __syncthreads();
  #pragma unroll 2
  for (int kc=8; kc<16; kc++){
    bf16x8 a0 = ldsA(sA, rbase+l15,    256, (kc-8)*4+kg);
    bf16x8 a1 = ldsA(sA, rbase+16+l15, 256, (kc-8)*4+kg);
    #pragma unroll
    for (int ct=0; ct<8; ct++){
      bf16x8 b = ldB(Wt, cbase+ct*16+l15, 512, kc*32+kg*8);
      acc[0][ct] = __builtin_amdgcn_mfma_f32_16x16x32_bf16(a0, b, acc[0][ct], 0,0,0);
      acc[1][ct] = __builtin_amdgcn_mfma_f32_16x16x32_bf16(a1, b, acc[1][ct], 0,0,0);
    }
  }
  __syncthreads();
  #pragma unroll
  for (int rt=0;rt<2;rt++)
  #pragma unroll
  for (int ct=0; ct<8; ct++){
    int col = cbase + ct*16 + l15;
    #pragma unroll
    for (int r=0;r<4;r++){
      int row = rbase + rt*16 + kg*4 + r;
      m[(size_t)(e0+row)*DEM + col] = f2us(silu_f(acc[rt][ct][r]));
    }
  }
}

// ---------------- fused gate + segment-sum (SEQUENTIAL: edges tgt-sorted) ----------------
__global__ void __launch_bounds__(256)
k_gseg_seq(const int* __restrict__ off, const u16* __restrict__ m,
           const u16* __restrict__ r16, const float* __restrict__ Wg,
           float* __restrict__ outp){
  __shared__ float sW[16*256];
  int n = blockIdx.x, j = threadIdx.x;
  for (int idx=j; idx<4096; idx+=256) sW[idx] = Wg[idx];
  __syncthreads();
  float s = 0.f;
  int beg = off[n], end = off[n+1];
  for (int e=beg; e<end; e++){
    const uint4* rp = (const uint4*)(r16 + (size_t)e*16);
    float rv[16];
    unp8(rp[0], rv); unp8(rp[1], rv+8);
    float g = 0.f;
    #pragma unroll
    for (int i=0;i<16;i++) g += rv[i]*sW[i*256+j];
    s += us2f(m[(size_t)e*DEM + j])*g;
  }
  outp[(size_t)n*DEM + j] = s;
}

// ---------------- Ewald ----------------
__global__ void k_sf(const float* __restrict__ cosk, const float* __restrict__ sink_,
                     const float* __restrict__ h, const float* __restrict__ kf,
                     float* __restrict__ sfre, float* __restrict__ sfim){
  int bk = blockIdx.x; int b = bk>>5, k = bk&31;
  int a = threadIdx.x;
  float sre=0.f, sim=0.f;
  int n0 = b*APM;
  for (int i=0;i<APM;i++){
    float c = cosk[(n0+i)*NK+k];
    float s = sink_[(n0+i)*NK+k];
    float hv = h[(size_t)(n0+i)*DA+a];
    sre += c*hv; sim += s*hv;
  }
  float f = kf[k*DA+a];
  sfre[(size_t)bk*DA+a] = sre*f;
  sfim[(size_t)bk*DA+a] = sim*f;
}

__global__ void k_ew(const float* __restrict__ cosk, const float* __restrict__ sink_,
                     const float* __restrict__ sfre, const float* __restrict__ sfim,
                     float* __restrict__ ew){
  int n = blockIdx.x; int a = threadIdx.x; int b = n>>8;
  float s=0.f;
  for (int k=0;k<NK;k++){
    s += cosk[n*NK+k]*sfre[(size_t)(b*NK+k)*DA+a] + sink_[n*NK+k]*sfim[(size_t)(b*NK+k)*DA+a];
  }
  ew[(size_t)n*DA+a]=s;
}

// ---------------- fused h update ----------------
__global__ void __launch_bounds__(128)
k_hup(const float* __restrict__ hsum, const float* __restrict__ ewb,
      const float* __restrict__ Wat, const float* __restrict__ Wew,
      float* __restrict__ h){
  __shared__ float sA[16*256];
  __shared__ float sB[16*128];
  int row0 = blockIdx.x*16;
  int j = threadIdx.x;
  for (int idx=j; idx<4096; idx+=128) sA[idx] = hsum[(size_t)row0*DEM + idx];
  for (int idx=j; idx<2048; idx+=128) sB[idx] = ewb[(size_t)row0*DA + idx];
  __syncthreads();
  float a1[16], a2[16];
  #pragma unroll
  for (int i=0;i<16;i++){ a1[i]=0.f; a2[i]=0.f; }
  for (int k=0;k<256;k++){
    float w = Wat[k*DA+j];
    #pragma unroll
    for (int i=0;i<16;i++) a1[i] += sA[i*256+k]*w;
  }
  for (int k=0;k<128;k++){
    float w = Wew[k*DA+j];
    #pragma unroll
    for (int i=0;i<16;i++) a2[i] += sB[i*128+k]*w;
  }
  #pragma unroll
  for (int i=0;i<16;i++){
    size_t oi = (size_t)(row0+i)*DA + j;
    h[oi] = (h[oi] + silu_f(a1[i]) + silu_f(a2[i]))*0.5773502691896258f;
  }
}

// ---------------- output ----------------
__global__ void k_out_atom(const float* __restrict__ Ea, const float* __restrict__ W1,
                           const float* __restrict__ W2, float* __restrict__ atom_e){
  __shared__ float red[128];
  int n = blockIdx.x; int j = threadIdx.x;
  const float* row = Ea + (size_t)n*DEM;
  float s=0.f;
  for (int k=0;k<DEM;k++) s += row[k]*W1[k*DA+j];
  float v = silu_f(s)*W2[j];
  red[j]=v; __syncthreads();
  for (int st=64; st>0; st>>=1){ if (j<st) red[j]+=red[j+st]; __syncthreads(); }
  if (j==0) atom_e[n]=red[0];
}

__global__ void k_out_mol(const float* __restrict__ atom_e, float* __restrict__ out){
  __shared__ float red[256];
  int b = blockIdx.x; int t = threadIdx.x;
  red[t] = atom_e[b*APM+t]; __syncthreads();
  for (int st=128; st>0; st>>=1){ if (t<st) red[t]+=red[t+st]; __syncthreads(); }
  if (t==0) out[b]=red[0];
}

extern "C" void kernel_launch(void* const* d_in, const int* in_sizes, int n_in,
                              void* d_out, int out_size, void* d_ws, size_t ws_size,
                              hipStream_t stream){
  (void)in_sizes; (void)n_in; (void)out_size;
  const float* pos    = (const float*)d_in[0];
  const float* atab   = (const float*)d_in[1];
  const float* W_edge = (const float*)d_in[2];
  const float* b_edge = (const float*)d_in[3];
  const float* W_rbf3 = (const float*)d_in[4];
  const float* W_rbf3E= (const float*)d_in[5];
  const float* W_cbf3 = (const float*)d_in[6];
  const float* W_ba   = (const float*)d_in[7];
  const float* W_dt   = (const float*)d_in[8];
  const float* W_bil  = (const float*)d_in[9];
  const float* W_up   = (const float*)d_in[10];
  const float* W_r1   = (const float*)d_in[11];
  const float* W_r2   = (const float*)d_in[12];
  const float* W_rbfh = (const float*)d_in[13];
  const float* W_h    = (const float*)d_in[14];
  const float* W_atom = (const float*)d_in[15];
  const float* kgrid  = (const float*)d_in[16];
  const float* krbfv  = (const float*)d_in[17];
  const float* W_dk   = (const float*)d_in[18];
  const float* W_kf   = (const float*)d_in[19];
  const float* W_ewm  = (const float*)d_in[20];
  const float* W_cat  = (const float*)d_in[21];
  const float* W_rbfo = (const float*)d_in[22];
  const float* W_oute = (const float*)d_in[23];
  const float* W_o1   = (const float*)d_in[24];
  const float* W_o2   = (const float*)d_in[25];
  const int* z     = (const int*)d_in[26];
  const int* esrc  = (const int*)d_in[27];
  const int* etgt  = (const int*)d_in[28];
  const int* id3ba = (const int*)d_in[29];
  const int* id3ca = (const int*)d_in[30];
  float* out = (float*)d_out;

  // ---- workspace carve (bytes), ~207 MiB ----
  char* base = (char*)d_ws;
  size_t off = 0;
  auto alloc = [&](size_t bytes)->char*{
    char* p = base + off;
    off += (bytes + 255) & ~(size_t)255;
    return p;
  };
  u16*   m     = (u16*)  alloc((size_t)NE*DEM*2);     // 128 MiB (tgt-sorted edge order)
  float4* vecd = (float4*)alloc((size_t)NE*16);       // 4 MiB
  float* dlen  = (float*)alloc((size_t)NE*4);
  u16*   r16a  = (u16*)  alloc((size_t)NE*16*2);
  u16*   r16h  = (u16*)  alloc((size_t)NE*16*2);
  u16*   r16o  = (u16*)  alloc((size_t)NE*16*2);
  float* h     = (float*)alloc((size_t)NA*DA*4);
  float* cosk  = (float*)alloc((size_t)NA*NK*4);
  float* sinkb = (float*)alloc((size_t)NA*NK*4);
  float* sfre  = (float*)alloc((size_t)NB*NK*DA*4);
  float* sfim  = (float*)alloc((size_t)NB*NK*DA*4);
  float* kf    = (float*)alloc((size_t)NK*DA*4);
  float* atome = (float*)alloc((size_t)NA*4);
  char*  scr   = alloc((size_t)24*1024*1024);         // union region
  int* tgt_off = (int*)alloc((size_t)(NA+1)*4);
  int* tgt_list= (int*)alloc((size_t)NE*4);
  int* iperm   = (int*)alloc((size_t)NE*4);           // orig edge -> sorted pos
  int* esrc_p  = (int*)alloc((size_t)NE*4);
  int* etgt_p  = (int*)alloc((size_t)NE*4);
  int* ca_off  = (int*)alloc((size_t)(NE+1)*4);
  int* ca_list = (int*)alloc((size_t)NT*4);           // iperm[id3_ba] VALUES
  int* parts   = (int*)alloc((size_t)1024*4);
  // bf16 transposed weights
  u16* wt_edge = (u16*)alloc((size_t)256*384*2);
  u16* wt_ba   = (u16*)alloc((size_t)2*256*256*2);
  u16* wt_r3e  = (u16*)alloc((size_t)2*256*32*2);
  u16* wt_dt   = (u16*)alloc((size_t)2*32*256*2);
  u16* wt_up   = (u16*)alloc((size_t)2*256*64*2);
  u16* wt_r1   = (u16*)alloc((size_t)2*256*256*2);
  u16* wt_r2   = (u16*)alloc((size_t)2*256*256*2);
  u16* wt_cat  = (u16*)alloc((size_t)2*256*512*2);
  u16* wt_cbf  = (u16*)alloc((size_t)112*128*2);
  u16* wt_bil  = (u16*)alloc((size_t)2*64*512*2);
  size_t need = off;
  if (ws_size < need) return;  // diagnostic: zero output => ws too small

  // scratch aliases
  u16*   xtrip = (u16*)scr;
  float* hsum  = (float*)scr;
  float* ewb   = (float*)(scr + (size_t)16*1024*1024);
  int* tmpi    = (int*)r16a;   // CSR temps (pre-phase, before r16 written)
  int* tgt_cnt = tmpi;
  int* tgt_loc = tmpi + NA;
  int* tgt_cur = tmpi + 2*NA;
  int* ca_cnt  = tmpi + 3*NA;
  int* ca_loc  = ca_cnt + NE;
  int* ca_cur  = ca_loc + NE;

  // ---- merged weight prep (bf16 W^T) ----
  WprepTable wt;
  int wn = 0;
  auto addw = [&](const float* src, u16* dst, int K, int N, int Kpad){
    wt.d[wn].src = src; wt.d[wn].dst = dst; wt.d[wn].K = K; wt.d[wn].N = N;
    wt.d[wn].Kpad = Kpad; wt.d[wn].elems = N*Kpad; wn++;
  };
  addw(W_edge, wt_edge, 384, 256, 384);
  for (int l=0; l<2; l++){
    addw(W_ba  + (size_t)l*256*256, wt_ba  + (size_t)l*256*256, 256, 256, 256);
    addw(W_rbf3E+(size_t)l*16*256,  wt_r3e + (size_t)l*256*32,  16,  256, 32);
    addw(W_dt  + (size_t)l*256*32,  wt_dt  + (size_t)l*32*256,  256, 32,  256);
    addw(W_up  + (size_t)l*64*256,  wt_up  + (size_t)l*256*64,  64,  256, 64);
    addw(W_r1  + (size_t)l*256*256, wt_r1  + (size_t)l*256*256, 256, 256, 256);
    addw(W_r2  + (size_t)l*256*256, wt_r2  + (size_t)l*256*256, 256, 256, 256);
    addw(W_cat + (size_t)l*512*256, wt_cat + (size_t)l*256*512, 512, 256, 512);
  }
  wt.n = wn;
  long long wtot = 0;
  for (int q=0;q<wn;q++) wtot += wt.d[q].elems;
  k_wprep_all<<<(int)((wtot+255)/256), 256, 0, stream>>>(wt);
  {
    WprepTable wb; int bn=0;
    auto addb = [&](const float* src, u16* dst, int K, int N, int Kpad){
      wb.d[bn].src=src; wb.d[bn].dst=dst; wb.d[bn].K=K; wb.d[bn].N=N;
      wb.d[bn].Kpad=Kpad; wb.d[bn].elems=N*Kpad; bn++;
    };
    addb(W_bil, wt_bil, 512, 64, 512);
    addb(W_bil + (size_t)512*64, wt_bil + (size_t)64*512, 512, 64, 512);
    wb.n = bn;
    long long btot = 0;
    for (int q=0;q<bn;q++) btot += wb.d[q].elems;
    k_wprep_all<<<(int)((btot+255)/256), 256, 0, stream>>>(wb);
  }
  k_wprep_cbf<<<(112*128+255)/256, 256, 0, stream>>>(W_cbf3, wt_cbf);

  // ---- CSR: edge_tgt -> atoms (gives tgt-sorted edge permutation) ----
  k_zero<<<NA/256, 256, 0, stream>>>(tgt_cnt, NA);
  k_count<<<NE/256, 256, 0, stream>>>(etgt, NE, tgt_cnt);
  k_scan1<<<NA/256, 256, 0, stream>>>(tgt_cnt, NA, tgt_loc, parts);
  k_scan2<<<1, 256, 0, stream>>>(parts, NA/256);
  k_scan3<<<NA/256, 256, 0, stream>>>(tgt_loc, parts, tgt_cnt, NA, tgt_off);
  k_copy_int<<<NA/256, 256, 0, stream>>>(tgt_off, NA, tgt_cur);
  k_fill<<<NE/256, 256, 0, stream>>>(etgt, NE, tgt_cur, tgt_list);
  k_iperm<<<NE/256, 256, 0, stream>>>(tgt_list, NE, iperm);
  k_permute2<<<NE/256, 256, 0, stream>>>(tgt_list, esrc, etgt, NE, esrc_p, etgt_p);

  // ---- geometry in permuted edge space ----
  k_geom<<<NE/256, 256, 0, stream>>>(pos, esrc_p, etgt_p, vecd, dlen);

  // ---- CSR: id3_ca -> permuted edges (values = iperm[id3_ba]) ----
  k_zero<<<NE/256, 256, 0, stream>>>(ca_cnt, NE);
  k_count_map<<<NT/256, 256, 0, stream>>>(id3ca, iperm, NT, ca_cnt);
  k_scan1<<<NE/256, 256, 0, stream>>>(ca_cnt, NE, ca_loc, parts);
  k_scan2<<<1, 256, 0, stream>>>(parts, NE/256);
  k_scan3<<<NE/256, 256, 0, stream>>>(ca_loc, parts, ca_cnt, NE, ca_off);
  k_copy_int<<<NE/256, 256, 0, stream>>>(ca_off, NE, ca_cur);
  k_fill_valmap<<<NT/256, 256, 0, stream>>>(id3ca, id3ba, iperm, NT, ca_cur, ca_list);

  // ---- bases ----
  k_rbf16<<<NE/4, 256, 0, stream>>>(dlen, W_rbf3, W_rbfh, W_rbfo, r16a, r16h, r16o);
  k_gather_h<<<NA*DA/256, 256, 0, stream>>>(atab, z, h);
  k_kdot<<<NA*NK/256, 256, 0, stream>>>(pos, kgrid, cosk, sinkb);
  k_kf<<<1, 256, 0, stream>>>(krbfv, W_dk, W_kf, kf);
  k_edgeinit_mx<<<NE/64, 256, 0, stream>>>(h, dlen, wt_edge, b_edge, esrc_p, etgt_p, m);

  // ---- interaction blocks ----
  for (int l=0; l<2; l++){
    k_ba_dt_mx<<<NE/32, 256, 0, stream>>>(m, wt_ba + (size_t)l*256*256,
                                          r16a, wt_r3e + (size_t)l*256*32,
                                          wt_dt + (size_t)l*32*256, xtrip);
    k_trip<<<NE/16, 256, 0, stream>>>(ca_off, ca_list, vecd, dlen, wt_cbf,
                                      xtrip, wt_bil + (size_t)l*64*512,
                                      wt_up + (size_t)l*256*64, m);
    k_res_mx<<<NE/64, 256, 0, stream>>>(wt_r1 + (size_t)l*256*256,
                                        wt_r2 + (size_t)l*256*256, m);
    k_gseg_seq<<<NA, 256, 0, stream>>>(tgt_off, m, r16h, W_h + (size_t)l*16*DEM, hsum);
    k_sf<<<NB*NK, 128, 0, stream>>>(cosk, sinkb, h, kf, sfre, sfim);
    k_ew<<<NA, 128, 0, stream>>>(cosk, sinkb, sfre, sfim, ewb);
    k_hup<<<NA/16, 128, 0, stream>>>(hsum, ewb, W_atom + (size_t)l*DEM*DA,
                                     W_ewm + (size_t)l*DA*DA, h);
    k_catref_mx<<<NE/64, 256, 0, stream>>>(h, wt_cat + (size_t)l*256*512, esrc_p, etgt_p, m);
  }

  // ---- output ----
  k_gseg_seq<<<NA, 256, 0, stream>>>(tgt_off, m, r16o, W_oute, hsum);
  k_out_atom<<<NA, 128, 0, stream>>>(hsum, W_o1, W_o2, atome);
  k_out_mol<<<NB, 256, 0, stream>>>(atome, out);
}